// Round 4
// baseline (74.688 us; speedup 1.0000x reference)
//
#include <hip/hip_runtime.h>

#define NB 255              // branches; heap node id == branch id for a perfect tree
#define DEPTH 8
#define F 32
#define N_ROWS 524288

// Select v[f] (f in [0,32)) from 32 registers via a 5-level cndmask tree.
// ~31 v_cndmask + 5 v_cmp; dependent latency ~12 cy vs ~240 cy for an LDS
// round-trip. All indices compile-time constant -> stays in registers.
__device__ __forceinline__ float sel32(const float* v, int f) {
    float a[16];
#pragma unroll
    for (int i = 0; i < 16; ++i) a[i] = (f & 1) ? v[2 * i + 1] : v[2 * i];
    float b[8];
#pragma unroll
    for (int i = 0; i < 8; ++i) b[i] = (f & 2) ? a[2 * i + 1] : a[2 * i];
    float c[4];
#pragma unroll
    for (int i = 0; i < 4; ++i) c[i] = (f & 4) ? b[2 * i + 1] : b[2 * i];
    float d0 = (f & 8) ? c[1] : c[0];
    float d1 = (f & 8) ? c[3] : c[2];
    return (f & 16) ? d1 : d0;
}

__global__ __launch_bounds__(256) void tree_regsel_kernel(
    const float* __restrict__ x,
    const int*   __restrict__ feature,
    const float* __restrict__ threshold,
    const float* __restrict__ value,
    float*       __restrict__ out)
{
    __shared__ int2 s_node[256];   // {feature, bitcast(threshold)}

    const int tid  = threadIdx.x;
    const int lane = tid & 63;

    // Every wave redundantly stages identical table values -> benign duplicate
    // writes; each wave depends only on its OWN ds_writes (no barrier needed).
#pragma unroll
    for (int k = 0; k < 4; ++k) {
        int e = lane + 64 * k;
        if (e < NB) s_node[e] = make_int2(feature[e], __float_as_int(threshold[e]));
    }

    // One row per thread, kept entirely in registers.
    const long long row = (long long)blockIdx.x * 256 + tid;
    const float4* xg = reinterpret_cast<const float4*>(x + row * F);
    float v[32];
#pragma unroll
    for (int j = 0; j < 8; ++j) {
        float4 t = xg[j];
        v[4 * j + 0] = t.x; v[4 * j + 1] = t.y;
        v[4 * j + 2] = t.z; v[4 * j + 3] = t.w;
    }

    // Heap traversal: per level one divergent ds_read_b64 (table) + select tree.
    int node = 0;
#pragma unroll
    for (int d = 0; d < DEPTH; ++d) {
        int2  nd = s_node[node];
        float t  = __int_as_float(nd.y);
        node = 2 * node + 1 + (sel32(v, nd.x) > t ? 1 : 0);
    }
    const int leaf = node - NB;

    // Leaf value gather (8 KB table, cache-resident) + coalesced-enough store.
    const float4* v4 = reinterpret_cast<const float4*>(value + (size_t)leaf * 8);
    float4 o0 = v4[0];
    float4 o1 = v4[1];
    float4* o = reinterpret_cast<float4*>(out + row * 8);
    o[0] = o0;
    o[1] = o1;
}

extern "C" void kernel_launch(void* const* d_in, const int* in_sizes, int n_in,
                              void* d_out, int out_size, void* d_ws, size_t ws_size,
                              hipStream_t stream) {
    (void)in_sizes; (void)n_in; (void)d_ws; (void)ws_size; (void)out_size;
    const float* x         = (const float*)d_in[0];
    const int*   feature   = (const int*)d_in[1];
    const float* threshold = (const float*)d_in[2];
    // d_in[3] = cond, d_in[4] = cond_mask — not needed (heap traversal is exact)
    const float* value     = (const float*)d_in[5];
    float*       out       = (float*)d_out;

    dim3 grid(N_ROWS / 256);   // 2048 blocks
    dim3 block(256);
    tree_regsel_kernel<<<grid, block, 0, stream>>>(x, feature, threshold, value, out);
}

// Round 5
// 19.142 us; speedup vs baseline: 3.9018x; 3.9018x over previous
//
#include <hip/hip_runtime.h>

#define NB 255              // branches; heap node id == branch id for a perfect tree
#define DEPTH 8
#define F 32
#define XSTRIDE 33          // ODD stride: gather bank = (lane + f) % 32 -> 2-way = free
#define WAVES 4
#define N_ROWS 524288

__global__ __launch_bounds__(256) void tree_lds33_kernel(
    const float* __restrict__ x,
    const int*   __restrict__ feature,
    const float* __restrict__ threshold,
    const float* __restrict__ value,
    float*       __restrict__ out)
{
    __shared__ float xs[WAVES][64 * XSTRIDE];   // per-wave 64-row tile, odd stride
    __shared__ int   s_feat[256];               // stride-4B tables: conflict-free gather
    __shared__ float s_thr[256];

    const int tid  = threadIdx.x;
    const int lane = tid & 63;
    const int wid  = tid >> 6;

    // Per-wave redundant table staging: identical values -> benign race, and each
    // wave depends only on its OWN in-order DS ops => no __syncthreads anywhere.
    #pragma unroll
    for (int k = 0; k < 4; ++k) {
        int e = lane + 64 * k;
        if (e < NB) { s_feat[e] = feature[e]; s_thr[e] = threshold[e]; }
    }

    const long long row0 = ((long long)blockIdx.x * WAVES + wid) * 64;
    const float4*   xg   = reinterpret_cast<const float4*>(x + row0 * F);

    // Coalesced read of this wave's 64x32 tile (8 dwordx4 per lane, all in flight).
    float4 A[8];
    #pragma unroll
    for (int j = 0; j < 8; ++j) A[j] = xg[j * 64 + lane];

    // Stage to LDS at odd stride. Row base = 132 B (not 16-aligned) => b32 writes;
    // write banks = (row + 4c + e) % 32, at most 2-way => free.
    float* myxs = xs[wid];
    #pragma unroll
    for (int j = 0; j < 8; ++j) {
        int f4 = j * 64 + lane;        // float4 index within the 64x32 tile
        int r  = f4 >> 3;              // 8 float4 per row
        int c  = (f4 & 7) * 4;
        float* p = &myxs[r * XSTRIDE + c];
        p[0] = A[j].x; p[1] = A[j].y; p[2] = A[j].z; p[3] = A[j].w;
    }

    // Heap traversal: 8 dependent {s_feat/s_thr read, x gather, step}; every LDS
    // access pattern above is <=2-way banked (free per m136).
    const float* row_x = &myxs[lane * XSTRIDE];
    int node = 0;
    #pragma unroll
    for (int d = 0; d < DEPTH; ++d) {
        int   f = s_feat[node];
        float t = s_thr[node];
        node = 2 * node + 1 + (row_x[f] > t ? 1 : 0);
    }
    const int leaf = node - NB;

    // Leaf value gather (8 KB, cache-resident) + coalesced store.
    const float4* v4 = reinterpret_cast<const float4*>(value + (size_t)leaf * 8);
    float4 o0 = v4[0];
    float4 o1 = v4[1];
    float4* o = reinterpret_cast<float4*>(out + (row0 + lane) * 8);
    o[0] = o0;
    o[1] = o1;
}

extern "C" void kernel_launch(void* const* d_in, const int* in_sizes, int n_in,
                              void* d_out, int out_size, void* d_ws, size_t ws_size,
                              hipStream_t stream) {
    (void)in_sizes; (void)n_in; (void)d_ws; (void)ws_size; (void)out_size;
    const float* x         = (const float*)d_in[0];
    const int*   feature   = (const int*)d_in[1];
    const float* threshold = (const float*)d_in[2];
    // d_in[3] = cond, d_in[4] = cond_mask — not needed (heap traversal is exact)
    const float* value     = (const float*)d_in[5];
    float*       out       = (float*)d_out;

    dim3 grid(N_ROWS / (WAVES * 64));   // 2048 blocks
    dim3 block(256);
    tree_lds33_kernel<<<grid, block, 0, stream>>>(x, feature, threshold, value, out);
}